// Round 7
// baseline (148.314 us; speedup 1.0000x reference)
//
#include <hip/hip_runtime.h>
#include <stdint.h>

#define D_DIM 128
#define NROW 8192          // 2B
#define L2EPS 1e-12f
#define LOG2E_X10 14.426950408889634f   // 10 / ln(2): exp(s*10) = 2^(s*LOG2E_X10)
#define LN2 0.6931471805599453f

typedef __attribute__((ext_vector_type(8))) short short8;
typedef __attribute__((ext_vector_type(4))) float f32x4;

static __device__ inline ushort f2bf(float f) {
    union { float f; uint32_t u; } v; v.f = f;
    uint32_t u = v.u;
    uint32_t r = (u + 0x7fffu + ((u >> 16) & 1u)) >> 16;   // RNE
    return (ushort)r;
}

struct BF { short8 v[4]; };

static __device__ inline void load_b(BF& d, const ushort* p) {
#pragma unroll
    for (int kk = 0; kk < 4; kk++)
        d.v[kk] = *(const short8*)(p + kk * 32);
}

// K1: L2-normalize rows of [x_i; x_j] -> bf16 z (B operand) and bf16
// z_s = z * 10/ln2 (A operand; MFMA output is then the exp2 argument).
__global__ __launch_bounds__(256) void k_normalize(
        const float* __restrict__ xi, const float* __restrict__ xj,
        ushort* __restrict__ z, ushort* __restrict__ z_s,
        float* __restrict__ pos_acc) {
    const int wave = threadIdx.x >> 6;
    const int lane = threadIdx.x & 63;
    const int row = blockIdx.x * 4 + wave;
    const float* src = (row < 4096) ? (xi + (size_t)row * D_DIM)
                                    : (xj + (size_t)(row - 4096) * D_DIM);
    float2 v = *(const float2*)(src + lane * 2);
    float ss = v.x * v.x + v.y * v.y;
#pragma unroll
    for (int m = 32; m >= 1; m >>= 1) ss += __shfl_xor(ss, m, 64);
    const float scale = 1.0f / fmaxf(sqrtf(ss), L2EPS);
    const float scale_s = scale * LOG2E_X10;
    ushort2 o, os;
    o.x  = f2bf(v.x * scale);    o.y  = f2bf(v.y * scale);
    os.x = f2bf(v.x * scale_s);  os.y = f2bf(v.y * scale_s);
    *(ushort2*)(z   + (size_t)row * D_DIM + lane * 2) = o;
    *(ushort2*)(z_s + (size_t)row * D_DIM + lane * 2) = os;

    if (blockIdx.x == 0 && threadIdx.x == 0) pos_acc[0] = 0.0f;
}

// K2: LDS-free fused GEMM. Block (rb=bid>>4, cc=bid&15) computes
// sim*10/ln2 for rows [rb*128,+128) x cols [cc*512,+512), K=128 entirely in
// registers. A-fragments: 8 direct global loads of z_s (one-time). B: 32
// tiles of 16 cols; per tile 4 global_load_dwordx4 per lane straight from
// L1/L2 (all 4 waves read identical addresses -> L1 x4 reuse; cc==bid&15
// aligns with XCD round-robin -> per-XCD L2 hot set ~256 KB). No LDS, no
// barriers, no vmcnt(0) drains; prefetch-distance-1 pipeline per wave.
// Epilogue: v_exp + v_add per element. Row partials -> denom_part[cc][row].
__global__ __launch_bounds__(256) void k_gemm(
        const ushort* __restrict__ z, const ushort* __restrict__ z_s,
        float* __restrict__ denom_part, float* __restrict__ pos_acc) {
    const int bid = blockIdx.x;
    const int t = threadIdx.x;
    const int wave = t >> 6, lane = t & 63;
    const int quad = lane >> 4, lc = lane & 15;

    const int rb = bid >> 4;            // row band 0..63 (128 rows)
    const int cc = bid & 15;            // col chunk 0..15 (512 cols)
    const int rowbase = rb * 128;
    const int colbase = cc * 512;

    // A fragments, direct from global z_s. Lane reads 16 B at
    // row(rowbase + wave*32 + i*16 + lc), bytes kk*64 + quad*16.
    short8 afr[2][4];
    {
        const ushort* pa = z_s + (size_t)(rowbase + wave * 32 + lc) * D_DIM + quad * 8;
#pragma unroll
        for (int i = 0; i < 2; i++)
#pragma unroll
            for (int kk = 0; kk < 4; kk++)
                afr[i][kk] = *(const short8*)(pa + i * 16 * D_DIM + kk * 32);
    }

    const bool diagblk = (cc == (rb >> 2));
    const bool posblk  = (cc == ((rb ^ 32) >> 2));
    const int djbase = 8 * (rb & 3) + wave * 2;          // diag j for i=0,1
    const int pjbase = 8 * ((rb ^ 32) & 3) + wave * 2;   // pos j for i=0,1

    float rs[2][4] = {{0.f,0.f,0.f,0.f},{0.f,0.f,0.f,0.f}};
    float posp = 0.f;
    const int rgbase = rowbase + wave * 32 + quad * 4;   // + i*16 + r

    const ushort* pb = z + (size_t)(colbase + lc) * D_DIM + quad * 8;

    // One j-tile: 8 MFMA + 8 exp/add. rg==cg and cg==rg^4096 are globally
    // exact conditions (can only hold in diag/pos blocks respectively).
    auto body = [&](int j, const short8* bc) {
        f32x4 a0 = {0.f,0.f,0.f,0.f}, a1 = {0.f,0.f,0.f,0.f};
#pragma unroll
        for (int kk = 0; kk < 4; kk++) {
            a0 = __builtin_amdgcn_mfma_f32_16x16x32_bf16(afr[0][kk], bc[kk], a0, 0, 0, 0);
            a1 = __builtin_amdgcn_mfma_f32_16x16x32_bf16(afr[1][kk], bc[kk], a1, 0, 0, 0);
        }
        const unsigned dj = (unsigned)(j - djbase);
        const unsigned pj = (unsigned)(j - pjbase);
        if ((diagblk && dj < 2u) || (posblk && pj < 2u)) {  // wave-uniform, rare
            const int cg = colbase + j * 16 + lc;
#pragma unroll
            for (int i = 0; i < 2; i++) {
#pragma unroll
                for (int r = 0; r < 4; r++) {
                    const float s = (i ? a1 : a0)[r];
                    float e = exp2f(s);
                    const int rg = rgbase + i * 16 + r;
                    if (rg == cg) e = 0.f;             // exclude diagonal
                    if (cg == (rg ^ 4096)) posp += s;  // positive (scaled)
                    rs[i][r] += e;
                }
            }
        } else {
#pragma unroll
            for (int r = 0; r < 4; r++) {
                rs[0][r] += exp2f(a0[r]);
                rs[1][r] += exp2f(a1[r]);
            }
        }
    };

    BF b0, b1;
    load_b(b0, pb);
    for (int j = 0; j < 32; j += 2) {
        load_b(b1, pb + (size_t)(j + 1) * 16 * D_DIM);   // prefetch j+1
        body(j, b0.v);
        if (j < 30)
            load_b(b0, pb + (size_t)(j + 2) * 16 * D_DIM); // prefetch j+2
        body(j + 1, b1.v);
    }

    // Row partials: reduce over the 16 col-lanes, one store per row.
#pragma unroll
    for (int i = 0; i < 2; i++)
#pragma unroll
        for (int r = 0; r < 4; r++) {
            float v = rs[i][r];
            v += __shfl_xor(v, 1, 64);
            v += __shfl_xor(v, 2, 64);
            v += __shfl_xor(v, 4, 64);
            v += __shfl_xor(v, 8, 64);
            if (lc == 0)
                denom_part[(size_t)cc * NROW + rgbase + i * 16 + r] = v;
        }

    if (posblk) {
#pragma unroll
        for (int m = 32; m >= 1; m >>= 1) posp += __shfl_xor(posp, m, 64);
        if (lane == 0) atomicAdd(pos_acc, posp);
    }
}

// K3 (fused logsum+combine): one block, 1024 threads; each thread owns 8 rows.
// pos_acc holds sum of (sim*10/ln2) over positives -> *ln2 gives sum(sim*10).
__global__ __launch_bounds__(1024) void k_logsum(
        const float* __restrict__ denom_part, const float* __restrict__ pos_acc,
        float* __restrict__ out) {
    __shared__ float red[16];
    const int t = threadIdx.x;
    float v = 0.f;
#pragma unroll
    for (int rr = 0; rr < 8; rr++) {
        const int row = rr * 1024 + t;
        float d = 0.f;
#pragma unroll
        for (int p = 0; p < 16; p++) d += denom_part[(size_t)p * NROW + row];
        v += __logf(d);
    }
#pragma unroll
    for (int m = 32; m >= 1; m >>= 1) v += __shfl_xor(v, m, 64);
    if ((t & 63) == 0) red[t >> 6] = v;
    __syncthreads();
    if (t == 0) {
        float total = 0.f;
#pragma unroll
        for (int i = 0; i < 16; i++) total += red[i];
        out[0] = (total - pos_acc[0] * LN2) / (float)NROW;
    }
}

extern "C" void kernel_launch(void* const* d_in, const int* in_sizes, int n_in,
                              void* d_out, int out_size, void* d_ws, size_t ws_size,
                              hipStream_t stream) {
    const float* xi = (const float*)d_in[0];
    const float* xj = (const float*)d_in[1];
    ushort* z   = (ushort*)d_ws;                                 // 2 MB bf16
    ushort* z_s = z + (size_t)NROW * D_DIM;                      // 2 MB bf16 (scaled)
    float* denom_part = (float*)(z_s + (size_t)NROW * D_DIM);    // 16 x 8192 f32
    float* pos_acc = denom_part + 16 * NROW;
    float* out = (float*)d_out;

    hipLaunchKernelGGL(k_normalize, dim3(NROW / 4), dim3(256), 0, stream,
                       xi, xj, z, z_s, pos_acc);
    hipLaunchKernelGGL(k_gemm, dim3(1024), dim3(256), 0, stream,
                       z, z_s, denom_part, pos_acc);
    hipLaunchKernelGGL(k_logsum, dim3(1), dim3(1024), 0, stream,
                       denom_part, pos_acc, out);
}

// Round 8
// 86.411 us; speedup vs baseline: 1.7164x; 1.7164x over previous
//
#include <hip/hip_runtime.h>
#include <stdint.h>

#define D_DIM 128
#define NROW 8192          // 2B
#define L2EPS 1e-12f
#define SCALE_A 14.426950408889634f  // 10/ln2: MFMA out = sim*10/ln2 = exp2 arg
#define LN2 0.6931471805599453f

typedef __attribute__((ext_vector_type(4))) int   i32x4;
typedef __attribute__((ext_vector_type(8))) int   i32x8;
typedef __attribute__((ext_vector_type(4))) float f32x4;

#define AS1 __attribute__((address_space(1)))
#define AS3 __attribute__((address_space(3)))

static __device__ inline void gload_lds16(const void* g, void* l) {
    __builtin_amdgcn_global_load_lds((const AS1 uint32_t*)g, (AS3 uint32_t*)l, 16, 0, 0);
}

static __device__ inline i32x8 cat8(i32x4 lo, i32x4 hi) {
    i32x8 r;
    r[0] = lo[0]; r[1] = lo[1]; r[2] = lo[2]; r[3] = lo[3];
    r[4] = hi[0]; r[5] = hi[1]; r[6] = hi[2]; r[7] = hi[3];
    return r;
}

// K1: L2-normalize rows of [x_i; x_j]; emit fp8 e4m3:
//   z8  = fp8(z)            (B operand)
//   z8s = fp8(z * 10/ln2)   (A operand: MFMA output is the exp2 argument)
__global__ __launch_bounds__(256) void k_normalize(
        const float* __restrict__ xi, const float* __restrict__ xj,
        uint8_t* __restrict__ z8, uint8_t* __restrict__ z8s,
        float* __restrict__ pos_acc, float* __restrict__ logsum) {
    const int wave = threadIdx.x >> 6;
    const int lane = threadIdx.x & 63;
    const int row = blockIdx.x * 4 + wave;
    const float* src = (row < 4096) ? (xi + (size_t)row * D_DIM)
                                    : (xj + (size_t)(row - 4096) * D_DIM);
    float2 v = *(const float2*)(src + lane * 2);
    float ss = v.x * v.x + v.y * v.y;
#pragma unroll
    for (int m = 32; m >= 1; m >>= 1) ss += __shfl_xor(ss, m, 64);
    const float scale = 1.0f / fmaxf(sqrtf(ss), L2EPS);
    const float scale_a = scale * SCALE_A;
    const int pk_b = __builtin_amdgcn_cvt_pk_fp8_f32(v.x * scale,   v.y * scale,   0, false);
    const int pk_a = __builtin_amdgcn_cvt_pk_fp8_f32(v.x * scale_a, v.y * scale_a, 0, false);
    *(ushort*)(z8  + (size_t)row * D_DIM + lane * 2) = (ushort)pk_b;
    *(ushort*)(z8s + (size_t)row * D_DIM + lane * 2) = (ushort)pk_a;

    if (blockIdx.x == 0 && threadIdx.x == 0) { pos_acc[0] = 0.0f; logsum[0] = 0.0f; }
}

// K2: block (rb=bid>>5, cc=bid&31) computes exp2-arg = sim*10/ln2 for rows
// [rb*128,+128) x cols [cc*256,+256) with ONE mfma_scale_16x16x128 per
// (i,j)-tile (K=128 in a single instruction, scales = 1.0). B tile (32 KB
// fp8, XOR-swizzled 16B units) staged fully into LDS by DMA -> ONE barrier
// total; the 16-j-tile loop is barrier-free (ds_read -> MFMA -> exp only).
// A fragments load once, direct from global z8s. Row partials ->
// denom_part[cc][row] (single writer). ~5 blocks/CU resident.
__global__ __launch_bounds__(256) void k_gemm(
        const uint8_t* __restrict__ z8, const uint8_t* __restrict__ z8s,
        float* __restrict__ denom_part, float* __restrict__ pos_acc) {
    __shared__ __align__(16) uint8_t lds[32768];   // 256 cols x 128 B

    const int bid = blockIdx.x;
    const int t = threadIdx.x;
    const int wave = t >> 6, lane = t & 63;
    const int quad = lane >> 4, lc = lane & 15;

    const int rb = bid >> 5;            // row band 0..63 (128 rows)
    const int cc = bid & 31;            // col chunk 0..31 (256 cols)
    const int rowbase = rb * 128;
    const int colbase = cc * 256;

    // DMA whole B tile: 2048 x 16B slots. Slot s holds row r=s>>3, global
    // 16B-unit g = (s&7) ^ (r&7)  (XOR swizzle for conflict-free frag reads).
    {
        const uint8_t* zb = z8 + (size_t)colbase * D_DIM;
#pragma unroll
        for (int q = 0; q < 8; q++) {
            const int s = q * 256 + t;
            const int r = s >> 3;
            const int g = (s & 7) ^ (r & 7);
            gload_lds16(zb + (size_t)r * D_DIM + g * 16, &lds[s * 16]);
        }
    }

    // A fragments: lane holds 32 bytes of row (rowbase+wave*32+i*16+lc),
    // k-bytes [quad*32, +32) -> one i32x8 per i-tile. Direct global loads
    // (one-time; overlaps the DMA above).
    i32x8 afr[2];
    {
        const uint8_t* pa = z8s + (size_t)(rowbase + wave * 32 + lc) * D_DIM + quad * 32;
#pragma unroll
        for (int i = 0; i < 2; i++) {
            i32x4 lo = *(const i32x4*)(pa + i * 16 * D_DIM);
            i32x4 hi = *(const i32x4*)(pa + i * 16 * D_DIM + 16);
            afr[i] = cat8(lo, hi);
        }
    }

    asm volatile("s_waitcnt vmcnt(0)" ::: "memory");
    __syncthreads();   // the ONLY barrier: B tile resident from here on

    const bool diagblk = (cc == (rb >> 1));
    const int  j0d = (rb & 1) * 8 + wave * 2;      // wave's 32-row diag window
    const int  rbp = rb ^ 32;
    const bool posblk = (cc == (rbp >> 1));
    const int  j0p = (rbp & 1) * 8 + wave * 2;

    float rs[2][4] = {{0.f,0.f,0.f,0.f},{0.f,0.f,0.f,0.f}};
    float posp = 0.f;
    const int rgbase = rowbase + wave * 32 + quad * 4;   // + i*16 + r

#pragma unroll 4
    for (int j = 0; j < 16; j++) {
        // B fragment: row j*16+lc, k-bytes [quad*32,+32) = units quad*2,
        // quad*2+1, each XOR-swizzled by (lc&7).
        const int rowb = (j * 16 + lc) * D_DIM;
        i32x4 blo = *(const i32x4*)&lds[rowb + (((quad * 2)     ^ (lc & 7)) * 16)];
        i32x4 bhi = *(const i32x4*)&lds[rowb + (((quad * 2 + 1) ^ (lc & 7)) * 16)];
        const i32x8 bfr = cat8(blo, bhi);

        f32x4 z4 = {0.f, 0.f, 0.f, 0.f};
        f32x4 a0 = __builtin_amdgcn_mfma_scale_f32_16x16x128_f8f6f4(
                       afr[0], bfr, z4, 0, 0, 0, 127, 0, 127);
        f32x4 a1 = __builtin_amdgcn_mfma_scale_f32_16x16x128_f8f6f4(
                       afr[1], bfr, z4, 0, 0, 0, 127, 0, 127);

        const bool careful = (diagblk && (unsigned)(j - j0d) < 2u) ||
                             (posblk  && (unsigned)(j - j0p) < 2u);
        if (careful) {   // wave-uniform, rare; exact global conditions inside
            const int cg = colbase + j * 16 + lc;
#pragma unroll
            for (int i = 0; i < 2; i++) {
#pragma unroll
                for (int r = 0; r < 4; r++) {
                    const float s = (i ? a1 : a0)[r];
                    float e = exp2f(s);
                    const int rg = rgbase + i * 16 + r;
                    if (rg == cg) e = 0.f;             // exclude diagonal
                    if (cg == (rg ^ 4096)) posp += s;  // positive (scaled)
                    rs[i][r] += e;
                }
            }
        } else {
#pragma unroll
            for (int r = 0; r < 4; r++) {
                rs[0][r] += exp2f(a0[r]);
                rs[1][r] += exp2f(a1[r]);
            }
        }
    }

    // Row partials: reduce over the 16 col-lanes, one store per row.
#pragma unroll
    for (int i = 0; i < 2; i++)
#pragma unroll
        for (int r = 0; r < 4; r++) {
            float v = rs[i][r];
            v += __shfl_xor(v, 1, 64);
            v += __shfl_xor(v, 2, 64);
            v += __shfl_xor(v, 4, 64);
            v += __shfl_xor(v, 8, 64);
            if (lc == 0)
                denom_part[(size_t)cc * NROW + rgbase + i * 16 + r] = v;
        }

    if (posblk) {
#pragma unroll
        for (int m = 32; m >= 1; m >>= 1) posp += __shfl_xor(posp, m, 64);
        if (lane == 0) atomicAdd(pos_acc, posp);
    }
}

// K3: 32 blocks x 256 threads, one row per thread: sum 32 partials, log,
// wave-reduce, atomicAdd into logsum.
__global__ __launch_bounds__(256) void k_logsum(
        const float* __restrict__ denom_part, float* __restrict__ logsum) {
    const int row = blockIdx.x * 256 + threadIdx.x;
    float d = 0.f;
#pragma unroll
    for (int p = 0; p < 32; p++) d += denom_part[(size_t)p * NROW + row];
    float v = __logf(d);
#pragma unroll
    for (int m = 32; m >= 1; m >>= 1) v += __shfl_xor(v, m, 64);
    if ((threadIdx.x & 63) == 0) atomicAdd(logsum, v);
}

// K4: combine. pos_acc holds sum of sim*10/ln2 over positives -> *ln2.
__global__ void k_combine(const float* __restrict__ logsum,
                          const float* __restrict__ pos_acc,
                          float* __restrict__ out) {
    out[0] = (logsum[0] - pos_acc[0] * LN2) / (float)NROW;
}

extern "C" void kernel_launch(void* const* d_in, const int* in_sizes, int n_in,
                              void* d_out, int out_size, void* d_ws, size_t ws_size,
                              hipStream_t stream) {
    const float* xi = (const float*)d_in[0];
    const float* xj = (const float*)d_in[1];
    uint8_t* z8  = (uint8_t*)d_ws;                               // 1 MB fp8
    uint8_t* z8s = z8 + (size_t)NROW * D_DIM;                    // 1 MB fp8 (scaled)
    float* denom_part = (float*)(z8s + (size_t)NROW * D_DIM);    // 32 x 8192 f32
    float* pos_acc = denom_part + 32 * NROW;
    float* logsum = pos_acc + 1;
    float* out = (float*)d_out;

    hipLaunchKernelGGL(k_normalize, dim3(NROW / 4), dim3(256), 0, stream,
                       xi, xj, z8, z8s, pos_acc, logsum);
    hipLaunchKernelGGL(k_gemm, dim3(2048), dim3(256), 0, stream,
                       z8, z8s, denom_part, pos_acc);
    hipLaunchKernelGGL(k_logsum, dim3(NROW / 256), dim3(256), 0, stream,
                       denom_part, logsum);
    hipLaunchKernelGGL(k_combine, dim3(1), dim3(1), 0, stream,
                       logsum, pos_acc, out);
}